// Round 1
// baseline (203.689 us; speedup 1.0000x reference)
//
#include <hip/hip_runtime.h>

// Problem constants (from reference): B=128, A=512, N=256.
// out[b,a,n] = r_ij[b,a,n] + exp(-0.05*E * (zi*zj)^1.01 / (zi+zj)^1.1)
//   zi = atomic_numbers[b,a] (int 1..89), zj = atomic_numbers[b, neighbors[b,a,n]]
// Key insight: the "dist_edit" term has only 89*89 distinct values -> 8100-entry
// LDS lookup table, computed per block (cheap: ~32 exp/log chains per thread).

#define BB 128
#define AA 512
#define NN 256
#define ROWS 64           // a-rows per block -> grid = 128*512/64 = 1024 blocks
#define TPB 256

__global__ __launch_bounds__(TPB, 4) void RAN_72567767433723_kernel(
    const float* __restrict__ an,    // (B,A) float32 (integer-valued)
    const int*   __restrict__ nbrs,  // (B,A,N) int32 in [0,A)
    const float* __restrict__ rij,   // (B,A,N) float32
    float*       __restrict__ out)   // (B,A,N) float32
{
    __shared__ float tab[90 * 90];   // 32400 B
    __shared__ int   zrow[AA];       //  2048 B  -> total 34448 B => 4 blocks/CU

    const int tid = threadIdx.x;
    const int bid = blockIdx.x;
    const int b        = bid >> 3;          // 8 blocks per batch (A/ROWS)
    const int row_base = (bid & 7) * ROWS;

    // Stage this batch's atomic numbers as ints (values exactly representable).
    for (int i = tid; i < AA; i += TPB)
        zrow[i] = (int)(an[b * AA + i] + 0.5f);

    // Build the pair table. zi==0 / zj==0 entries are never read; clamp to keep
    // the fast-math chain finite.
    const float c = -0.05f * 2.718281828459045f;
    for (int idx = tid; idx < 90 * 90; idx += TPB) {
        int zi = idx / 90;
        int zj = idx - zi * 90;
        float p = fmaxf((float)(zi * zj), 1.0f);
        float s = fmaxf((float)(zi + zj), 1.0f);
        tab[idx] = __expf(c * __powf(p, 1.01f) / __powf(s, 1.1f));
    }
    __syncthreads();

    const int lane_row = tid >> 6;   // which of the 4 rows this iteration (wave-uniform)
    const int c4       = tid & 63;   // float4 slot within the row (N/4 = 64)

    #pragma unroll 4
    for (int it = 0; it < ROWS / 4; ++it) {
        const int a      = row_base + it * 4 + lane_row;
        const int tbase  = zrow[a] * 90;                  // wave-uniform LDS broadcast
        const size_t e   = ((size_t)(b * AA + a) * NN) + (size_t)c4 * 4;

        const int4   nb = *(const int4*)(nbrs + e);
        const float4 r  = *(const float4*)(rij + e);

        float4 o;
        o.x = r.x + tab[tbase + zrow[nb.x]];
        o.y = r.y + tab[tbase + zrow[nb.y]];
        o.z = r.z + tab[tbase + zrow[nb.z]];
        o.w = r.w + tab[tbase + zrow[nb.w]];

        *(float4*)(out + e) = o;
    }
}

extern "C" void kernel_launch(void* const* d_in, const int* in_sizes, int n_in,
                              void* d_out, int out_size, void* d_ws, size_t ws_size,
                              hipStream_t stream) {
    const float* an  = (const float*)d_in[0];   // atomic_numbers (B,A)
    const int*   nbr = (const int*)d_in[1];     // neighbors (B,A,N)
    const float* rij = (const float*)d_in[2];   // r_ij (B,A,N)
    float*       o   = (float*)d_out;

    const int grid = (BB * AA) / ROWS;          // 1024
    RAN_72567767433723_kernel<<<grid, TPB, 0, stream>>>(an, nbr, rij, o);
}

// Round 2
// 166.989 us; speedup vs baseline: 1.2198x; 1.2198x over previous
//
#include <hip/hip_runtime.h>

// B=128, A=512, N=256.
// out[b,a,n] = r_ij[b,a,n] + f(zi, zj),  f has only 89*89 distinct values.
// Round 2: f16 table (built ONCE into d_ws, copied to LDS), u16 zrow,
//          LDS 34.4->17.4 KB => 8 blocks/CU (100% occupancy), 2048 blocks,
//          nontemporal streaming loads/stores.

#define BB 128
#define AA 512
#define NN 256
#define ROWS 32            // a-rows per block -> grid = 128*512/32 = 2048
#define TPB 256
#define TABN 8192          // 90*90=8100 rounded up for clean 16B-vector copy

typedef int   v4i __attribute__((ext_vector_type(4)));
typedef float v4f __attribute__((ext_vector_type(4)));

__device__ __forceinline__ float tab_entry(int idx) {
    int zi = idx / 90, zj = idx - zi * 90;
    float p = fmaxf((float)(zi * zj), 1.0f);
    float s = fmaxf((float)(zi + zj), 1.0f);
    const float c = -0.05f * 2.718281828459045f;
    return __expf(c * __powf(p, 1.01f) / __powf(s, 1.1f));
}

__global__ void RAN_72567767433723_build_tab(_Float16* __restrict__ tabg) {
    int idx = blockIdx.x * blockDim.x + threadIdx.x;   // grid covers TABN
    tabg[idx] = (_Float16)tab_entry(idx);
}

template <bool LOAD_TAB>
__global__ __launch_bounds__(TPB, 8) void RAN_72567767433723_kernel(
    const float* __restrict__ an,    // (B,A) float32 (integer-valued 1..89)
    const int*   __restrict__ nbrs,  // (B,A,N) int32 in [0,A)
    const float* __restrict__ rij,   // (B,A,N) float32
    float*       __restrict__ out,   // (B,A,N) float32
    const _Float16* __restrict__ tabg)
{
    __shared__ _Float16       tab[TABN];  // 16384 B
    __shared__ unsigned short zz[AA];     //  1024 B -> 17408 B total => 8 blk/CU

    const int tid      = threadIdx.x;
    const int b        = blockIdx.x >> 4;            // 16 blocks per batch
    const int row_base = (blockIdx.x & 15) * ROWS;

    if (LOAD_TAB) {
        // coalesced 16B-per-lane copy: 4 iterations of 256 lanes
        #pragma unroll
        for (int i = 0; i < TABN * 2 / (16 * TPB); ++i) {
            int k = i * TPB + tid;
            ((v4i*)tab)[k] = ((const v4i*)tabg)[k];
        }
    } else {
        for (int idx = tid; idx < TABN; idx += TPB)
            tab[idx] = (_Float16)tab_entry(idx);
    }
    #pragma unroll
    for (int i = tid; i < AA; i += TPB)
        zz[i] = (unsigned short)(int)(an[b * AA + i] + 0.5f);
    __syncthreads();

    const int w = tid >> 6;   // wave id: one row per wave per iteration
    const int l = tid & 63;   // float4 slot within the row (N/4 = 64)

    #pragma unroll 2
    for (int it = 0; it < ROWS / 4; ++it) {
        const int a     = row_base + it * 4 + w;
        const int tb    = (int)zz[a] * 90;           // wave-uniform LDS broadcast
        const size_t e  = ((size_t)(b * AA + a)) * NN + (size_t)(l * 4);

        const v4i nb = __builtin_nontemporal_load((const v4i*)(nbrs + e));
        const v4f r  = __builtin_nontemporal_load((const v4f*)(rij + e));

        v4f o;
        o.x = r.x + (float)tab[tb + (int)zz[nb.x]];
        o.y = r.y + (float)tab[tb + (int)zz[nb.y]];
        o.z = r.z + (float)tab[tb + (int)zz[nb.z]];
        o.w = r.w + (float)tab[tb + (int)zz[nb.w]];

        __builtin_nontemporal_store(o, (v4f*)(out + e));
    }
}

extern "C" void kernel_launch(void* const* d_in, const int* in_sizes, int n_in,
                              void* d_out, int out_size, void* d_ws, size_t ws_size,
                              hipStream_t stream) {
    const float* an  = (const float*)d_in[0];
    const int*   nbr = (const int*)d_in[1];
    const float* rij = (const float*)d_in[2];
    float*       o   = (float*)d_out;

    const int grid = (BB * AA) / ROWS;   // 2048

    if (ws_size >= (size_t)TABN * sizeof(_Float16)) {
        _Float16* tabg = (_Float16*)d_ws;
        RAN_72567767433723_build_tab<<<TABN / TPB, TPB, 0, stream>>>(tabg);
        RAN_72567767433723_kernel<true><<<grid, TPB, 0, stream>>>(an, nbr, rij, o, tabg);
    } else {
        RAN_72567767433723_kernel<false><<<grid, TPB, 0, stream>>>(an, nbr, rij, o, nullptr);
    }
}